// Round 10
// baseline (35.747 us; speedup 1.0000x reference)
//
#include <hip/hip_runtime.h>
#include <hip/hip_bf16.h>

// AWQ 4-bit linear: out[32,11008] = x[32,4096] @ ((q - z)*s) + bias
// Round 10: (1) derived conflict-free LDS swizzle: col c -> slot
// s=((c&7)<<2)|(c>>3) (rotate puts word-bit into bank bit4), quad stored at
// KQ^((c>>1)&3); writes 2-way, b128 reads 2-way per 16-lane phase.
// (2) fp16 perm-dequant: v_perm gathers (k0,k1) nibble bytes per col,
// and_or builds exact fp16 (1024+n) pairs, pk_add(-(1024+z)) is an EXACT
// integer q-z, pk_mul by fp16 scale; f16 MFMA. Barrier-free per-wave
// staging, ring depth 3, KSPLIT=16, slab partials + reduce.

#define IN_F   4096
#define OUT_F  11008
#define WCOLS  1376
#define NCOLB  86                 // 11008/128
#define KSPLIT 16
#define CHUNK  (IN_F/KSPLIT)      // 256
#define NTILE  (CHUNK/32)         // 8
#define NBLK   (NCOLB*KSPLIT)     // 1376
#define MROWS  32
#define SLAB   (MROWS*OUT_F)      // floats per k-partial slab (352256)

typedef __attribute__((ext_vector_type(2))) _Float16 half2v;
typedef __attribute__((ext_vector_type(4))) _Float16 half4v;
typedef __attribute__((ext_vector_type(8))) _Float16 half8v;
typedef __attribute__((ext_vector_type(4))) float    f32x4;
typedef __attribute__((ext_vector_type(4))) int      int4v;

__device__ __forceinline__ f32x4 mfma16h(half8v a, half8v b, f32x4 c) {
  return __builtin_amdgcn_mfma_f32_16x16x32_f16(a, b, c, 0, 0, 0);
}
__device__ __forceinline__ half2v splat_h(float f) {
  unsigned short b = __builtin_bit_cast(unsigned short, (_Float16)f);
  unsigned int u = (unsigned int)b | ((unsigned int)b << 16);
  return __builtin_bit_cast(half2v, u);
}

__global__ void awq_init(const float* __restrict__ bias, float* __restrict__ out) {
  int o = blockIdx.x * 256 + threadIdx.x;
  out[blockIdx.y * OUT_F + o] = bias[o];
}

__global__ void xconv(const float* __restrict__ x, _Float16* __restrict__ xb) {
  int i = blockIdx.x * 256 + threadIdx.x;          // 128 blocks -> 32768 f32x4
  f32x4 v = ((const f32x4*)x)[i];
  half4v o;
  #pragma unroll
  for (int j = 0; j < 4; ++j) o[j] = (_Float16)v[j];
  ((half4v*)xb)[i] = o;
}

__global__ __launch_bounds__(256) void awq_reduce(
    const float* __restrict__ ws, const float* __restrict__ bias,
    float* __restrict__ out)
{
  const int i = blockIdx.x * 256 + threadIdx.x;    // f32x4 id, 88064 total
  const f32x4* w4 = (const f32x4*)ws;
  f32x4 s = w4[i];
  #pragma unroll
  for (int k = 1; k < KSPLIT; ++k) s += w4[k * (SLAB / 4) + i];
  const f32x4 b = *(const f32x4*)(bias + (i % (OUT_F / 4)) * 4);
  ((f32x4*)out)[i] = s + b;
}

template<bool PRE, bool TOWS>
__global__ __launch_bounds__(256, 4) void awq_main(
    const float* __restrict__ x, const _Float16* __restrict__ xb,
    const int* __restrict__ qw, const int* __restrict__ qz,
    const float* __restrict__ sc, float* __restrict__ outp)
{
  // Per-wave private staging, swizzled: [buf][wave][512 dwords] = 16 KB.
  __shared__ int lds[2][4][512];

  const int tid  = threadIdx.x;
  const int w    = tid >> 6;           // wave -> 32-col subtile
  const int lane = tid & 63;
  const int q4   = lane >> 4;          // MFMA k-octet
  const int cl   = lane & 15;          // MFMA col-in-frag
  const int ww   = lane & 3;           // dequant: word 0..3 -> cols 8ww..8ww+7
  const int kp2  = lane >> 2;          // dequant: k-pair 0..15
  const int qx   = kp2 >> 2;           // quad of kp
  const int kq   = kp2 & 3;            // kp within quad

  // Bijective XCD swizzle (1376 = 8*172)
  const int b  = blockIdx.x;
  const int L  = (b & 7) * (NBLK / 8) + (b >> 3);
  const int colblk = L % NCOLB;
  const int kchunk = L / NCOLB;

  const int cb  = colblk * 128;        // first output column
  const int wcb = colblk * 16;         // first packed word
  const int K0  = kchunk * CHUNK;
  const int g0  = kchunk * (CHUNK / 128);   // 2 groups per chunk
  const int wq  = wcb + 4 * w + ww;    // lane's packed-word column

  // group constants: raw staging -> fp16 splat pairs
  f32x4 sra, srb; int zrw;
  half2v nz[8], ss[8];
  auto load_group_raw = [&](int g) {
    sra = *(const f32x4*)(sc + g * OUT_F + cb + w * 32 + ww * 8);
    srb = *(const f32x4*)(sc + g * OUT_F + cb + w * 32 + ww * 8 + 4);
    zrw = qz[g * WCOLS + wq];
  };
  auto conv_group = [&]() {
    #pragma unroll
    for (int l = 0; l < 8; ++l) {
      const int sh = 4 * (l >> 1) + 16 * (l & 1);   // 4*REV[l]
      const int zi = (zrw >> sh) & 15;
      nz[l] = splat_h(-(float)(1024 + zi));
      ss[l] = splat_h((l < 4) ? sra[l] : srb[l - 4]);
    }
  };
  auto load_q = [&](int t, int& q0, int& q1) {
    const int r = (K0 + t * 32 + 2 * kp2) * WCOLS + wq;
    q0 = qw[r];
    q1 = qw[r + WCOLS];
  };
  auto load_a = [&](int t, int mf) -> half8v {
    const int m = cl + 16 * mf;
    const int k = K0 + t * 32 + q4 * 8;
    if constexpr (PRE) {
      return *(const half8v*)(xb + m * IN_F + k);
    } else {
      const f32x4* xp = (const f32x4*)(x + m * IN_F + k);
      f32x4 lo = xp[0], hi = xp[1];
      half8v af;
      #pragma unroll
      for (int j = 0; j < 4; ++j) { af[j] = (_Float16)lo[j]; af[4+j] = (_Float16)hi[j]; }
      return af;
    }
  };
  // read B frag (cols cl / cl+16, k = 8q4..8q4+7), swizzle-inverse of store
  auto read_b = [&](int p, int frag) -> half8v {
    const int s0 = ((cl & 7) << 2) | (cl >> 3);
    const int qp = (q4 ^ ((cl >> 1) & 3)) << 2;
    const int idx = (s0 + 2 * frag) * 16 + qp;
    return __builtin_bit_cast(half8v, *(const int4v*)&lds[p][w][idx]);
  };

  // ---- prologue
  load_group_raw(g0);
  conv_group();
  int q0a, q1a, q0b, q1b, q0c, q1c;
  load_q(0, q0a, q1a);
  load_q(1, q0b, q1b);
  load_q(2, q0c, q1c);
  f32x4 acc[2][2] = {};

  #pragma unroll 4
  for (int t = 0; t < NTILE; ++t) {
    half8v a0 = load_a(t, 0), a1 = load_a(t, 1);
    int q0n = 0, q1n = 0;
    if (t + 3 < NTILE) load_q(t + 3, q0n, q1n);            // ring refill
    if (t == 2) load_group_raw(g0 + 1);                    // raw 2 tiles early
    if (t == 4) conv_group();                              // group 1 live t>=4

    // fp16 perm-dequant: per col l, gather (k0,k1) nibble-bytes, build
    // exact 1024+n halves, exact pk (q-z), pk mul by fp16 scale.
    const int p  = t & 1;
    const int h0 = (unsigned)q0a >> 4;
    const int h1 = (unsigned)q1a >> 4;
    #pragma unroll
    for (int l = 0; l < 8; ++l) {
      const int pb = 2 * (l & 1) + (l >> 2);               // source byte
      const unsigned sel = (unsigned)(4 + pb) | ((unsigned)(4 + pb) << 8)
                         | ((unsigned)pb << 16) | ((unsigned)pb << 24);
      const int x0 = ((l >> 1) & 1) ? h0 : q0a;
      const int x1 = ((l >> 1) & 1) ? h1 : q1a;
      unsigned P = __builtin_amdgcn_perm((unsigned)x0, (unsigned)x1, sel);
      unsigned W = (P & 0x000F000Fu) | 0x64006400u;        // h2: 1024+n
      half2v wh = (__builtin_bit_cast(half2v, W) + nz[l]) * ss[l];
      // store col c=ww*8+l at slot l*4+ww, quad qx^((l>>1)&3), elem kq
      const int idx = (l * 4 + ww) * 16 + ((qx ^ ((l >> 1) & 3)) << 2) + kq;
      lds[p][w][idx] = __builtin_bit_cast(int, wh);
    }
    // no barrier: same-wave ds_write -> ds_read via lgkmcnt only

    half8v bf0 = read_b(p, 0);
    half8v bf1 = read_b(p, 1);

    acc[0][0] = mfma16h(a0, bf0, acc[0][0]);
    acc[0][1] = mfma16h(a0, bf1, acc[0][1]);
    acc[1][0] = mfma16h(a1, bf0, acc[1][0]);
    acc[1][1] = mfma16h(a1, bf1, acc[1][1]);

    q0a = q0b; q1a = q1b;
    q0b = q0c; q1b = q1c;
    q0c = q0n; q1c = q1n;
  }

  // ---- epilogue
  const int col0 = cb + w * 32 + cl;
  const int r0 = q4 * 4;
  if constexpr (TOWS) {
    float* wsp = outp + kchunk * SLAB;
    #pragma unroll
    for (int mf = 0; mf < 2; ++mf) {
      #pragma unroll
      for (int i = 0; i < 4; ++i) {
        const int row = mf * 16 + r0 + i;
        wsp[row * OUT_F + col0]      = acc[mf][0][i];
        wsp[row * OUT_F + col0 + 16] = acc[mf][1][i];
      }
    }
  } else {
    #pragma unroll
    for (int mf = 0; mf < 2; ++mf) {
      #pragma unroll
      for (int i = 0; i < 4; ++i) {
        const int row = mf * 16 + r0 + i;
        atomicAdd(outp + row * OUT_F + col0,      acc[mf][0][i]);
        atomicAdd(outp + row * OUT_F + col0 + 16, acc[mf][1][i]);
      }
    }
  }
}

extern "C" void kernel_launch(void* const* d_in, const int* in_sizes, int n_in,
                              void* d_out, int out_size, void* d_ws, size_t ws_size,
                              hipStream_t stream) {
  const float* x    = (const float*)d_in[0];
  const int*   qwp  = (const int*)d_in[1];
  const int*   qzp  = (const int*)d_in[2];
  const float* scp  = (const float*)d_in[3];
  const float* bias = (const float*)d_in[4];
  float* out = (float*)d_out;

  const size_t ws_part = (size_t)KSPLIT * SLAB * sizeof(float);   // 22.5 MB
  const size_t xb_sz   = (size_t)MROWS * IN_F * 2;                // 256 KB

  if (ws_size >= ws_part + xb_sz) {
    float* ws = (float*)d_ws;
    _Float16* xb = (_Float16*)((char*)d_ws + ws_part);
    xconv<<<128, 256, 0, stream>>>(x, xb);
    awq_main<true, true><<<NBLK, 256, 0, stream>>>(x, xb, qwp, qzp, scp, ws);
    awq_reduce<<<SLAB / 4 / 256, 256, 0, stream>>>(ws, bias, out);
  } else {
    awq_init<<<dim3(43, 32), 256, 0, stream>>>(bias, out);
    awq_main<false, false><<<NBLK, 256, 0, stream>>>(x, nullptr, qwp, qzp, scp, out);
  }
}